// Round 2
// 238.459 us; speedup vs baseline: 1.0676x; 1.0676x over previous
//
#include <hip/hip_runtime.h>
#include <hip/hip_bf16.h>
#include <math.h>

typedef unsigned short u16;
typedef __attribute__((ext_vector_type(8))) short bf16x8;
typedef __attribute__((ext_vector_type(4))) float f32x4;

#define BATCH 4
#define TSEQ  2048
#define HEADS 16
#define DK    64
#define EMB   1024
#define MROWS 8192            // B*T
#define NQKV  3072
#define PHT   ((size_t)MROWS * EMB)   // 8388608 elems per Q/K/V plane

__device__ __forceinline__ u16 f2bf(float f) {
    union { float f; unsigned int i; } v;
    v.f = f;
    unsigned int x = v.i;
    return (u16)((x + 0x7FFFu + ((x >> 16) & 1u)) >> 16);  // RNE
}

// packed 2xfp32 -> 2xbf16 (RNE) in one u32
__device__ __forceinline__ unsigned int pk2bf(float a, float b) {
    float2 f2; f2.x = a; f2.y = b;
    union { __hip_bfloat162 h; unsigned int u; } cv;
    cv.h = __float22bfloat162_rn(f2);
    return cv.u;
}

// async 16B global->LDS (dest = wave-uniform base + lane*16)
__device__ __forceinline__ void gl2lds16(const u16* g, u16* l) {
    __builtin_amdgcn_global_load_lds(
        (const __attribute__((address_space(1))) unsigned int*)g,
        (__attribute__((address_space(3))) unsigned int*)l, 16, 0, 0);
}

// ---------------------------------------------------------------------------
// prep: fp32 -> bf16 convert (X); both weight transposes in ONE launch
// ---------------------------------------------------------------------------
__global__ __launch_bounds__(256) void convert_x(const float* __restrict__ X,
                                                 u16* __restrict__ Xb) {
    int i = (blockIdx.x * 256 + threadIdx.x) * 4;
    float4 v = *(const float4*)&X[i];
    ushort4 o;
    o.x = f2bf(v.x); o.y = f2bf(v.y); o.z = f2bf(v.z); o.w = f2bf(v.w);
    *(ushort4*)&Xb[i] = o;
}

// bx < 96 -> Wqkv (N=3072); else Wo (N=1024). K=1024 for both.
__global__ __launch_bounds__(256) void transpose_both(const float* __restrict__ Wqkv,
                                                      const float* __restrict__ Wo,
                                                      u16* __restrict__ Wt,
                                                      u16* __restrict__ Wot) {
    __shared__ float tile[32][33];
    const int tx = threadIdx.x & 31, ty = threadIdx.x >> 5;  // 32 x 8
    const int K = 1024;
    const float* W;
    u16* D;
    int N, bx;
    if (blockIdx.x < 96) { W = Wqkv; D = Wt; N = 3072; bx = blockIdx.x; }
    else                 { W = Wo;   D = Wot; N = 1024; bx = blockIdx.x - 96; }
    const int by = blockIdx.y;
#pragma unroll
    for (int s = 0; s < 4; s++)
        tile[ty + 8 * s][tx] = W[(size_t)(by * 32 + ty + 8 * s) * N + bx * 32 + tx];
    __syncthreads();
#pragma unroll
    for (int s = 0; s < 4; s++)
        D[(size_t)(bx * 32 + ty + 8 * s) * K + by * 32 + tx] = f2bf(tile[tx][ty + 8 * s]);
}

// ---------------------------------------------------------------------------
// MFMA GEMM core v2: 128(M) x 256(N) tile, BK=64, 8 waves (2Mx4N), 512 thr.
// Triple-buffered LDS (3 x 48KB = 144KB), counted-vmcnt pipeline:
//   - prologue stages tiles 0,1,2 (6 gl2lds each, per wave)
//   - per tile: vmcnt(12) [2 tiles in flight] -> s_barrier -> ds_read frags
//     -> lgkmcnt(0) -> s_barrier -> stage tile kt+3 into freed buffer
//     -> setprio(1) 32 MFMA setprio(0)
// Raw s_barrier (NOT __syncthreads) so prefetch loads survive the barrier —
// this is the T3/T4 counted-vmcnt structure (never drain to 0 in main loop).
// LDS swizzle: global source chunk pre-XORed (p ^ (row&7)); reads apply the
// same XOR -> ds_read_b128 lands 2-way (free) instead of 16-way conflicts.
// ---------------------------------------------------------------------------
template <int KDIM>
__device__ __forceinline__ void gemm_core256(const u16* __restrict__ A,
                                             const u16* __restrict__ Bt,
                                             u16* pool,
                                             int m0, int n0, int wm, int wn,
                                             int tid, int lo, int quad,
                                             f32x4 (&acc)[4][4]) {
    constexpr int NT = KDIM / 64;

    // per-thread running global pointers (advance 64 elems per staged tile)
    const u16* ga[2];
    const u16* gb[4];
#pragma unroll
    for (int c = 0; c < 2; c++) {
        int chunk = c * 512 + tid, row = chunk >> 3, p = chunk & 7;
        ga[c] = A + (size_t)(m0 + row) * KDIM + (p ^ (row & 7)) * 8;
    }
#pragma unroll
    for (int c = 0; c < 4; c++) {
        int chunk = c * 512 + tid, row = chunk >> 3, p = chunk & 7;
        gb[c] = Bt + (size_t)(n0 + row) * KDIM + (p ^ (row & 7)) * 8;
    }

    auto stage = [&](int b) {   // 6 gl2lds per wave -> vmcnt +6
        u16* As = pool + b * 24576;
        u16* Bs = As + 8192;
#pragma unroll
        for (int c = 0; c < 2; c++) {
            gl2lds16(ga[c], As + (size_t)(c * 512 + tid) * 8);
            ga[c] += 64;
        }
#pragma unroll
        for (int c = 0; c < 4; c++) {
            gl2lds16(gb[c], Bs + (size_t)(c * 512 + tid) * 8);
            gb[c] += 64;
        }
    };

    auto comp = [&](int b, bool dostage) {
        const u16* As = pool + b * 24576;
        const u16* Bs = As + 8192;
        __builtin_amdgcn_s_barrier();        // B1: tile-kt LDS visible to all
        bf16x8 af[2][4], bw[2][4];
#pragma unroll
        for (int ks = 0; ks < 2; ks++) {
#pragma unroll
            for (int i = 0; i < 4; i++) {
                int r = wm + i * 16 + lo;
                af[ks][i] = *(const bf16x8*)&As[r * 64 + ((ks * 4 + quad) ^ (r & 7)) * 8];
            }
#pragma unroll
            for (int j = 0; j < 4; j++) {
                int r = wn + j * 16 + lo;
                bw[ks][j] = *(const bf16x8*)&Bs[r * 64 + ((ks * 4 + quad) ^ (r & 7)) * 8];
            }
        }
        asm volatile("s_waitcnt lgkmcnt(0)" ::: "memory");
        __builtin_amdgcn_s_barrier();        // B2: buffer b free for overwrite
        if (dostage) stage(b);               // tile kt+3; flies across 2+ tiles
        __builtin_amdgcn_s_setprio(1);
#pragma unroll
        for (int ks = 0; ks < 2; ks++)
#pragma unroll
            for (int i = 0; i < 4; i++)
#pragma unroll
                for (int j = 0; j < 4; j++)
                    acc[i][j] = __builtin_amdgcn_mfma_f32_16x16x32_bf16(
                        af[ks][i], bw[ks][j], acc[i][j], 0, 0, 0);
        __builtin_amdgcn_s_setprio(0);
    };

    stage(0); stage(1); stage(2);            // 18 loads in flight
    int bsel = 0;
    for (int kt = 0; kt < NT - 3; kt++) {
        asm volatile("s_waitcnt vmcnt(12)" ::: "memory");   // tile kt landed
        comp(bsel, true);
        bsel = (bsel == 2) ? 0 : bsel + 1;
    }
    asm volatile("s_waitcnt vmcnt(12)" ::: "memory");
    comp(bsel, false); bsel = (bsel == 2) ? 0 : bsel + 1;
    asm volatile("s_waitcnt vmcnt(6)" ::: "memory");
    comp(bsel, false); bsel = (bsel == 2) ? 0 : bsel + 1;
    asm volatile("s_waitcnt vmcnt(0)" ::: "memory");
    comp(bsel, false);
}

// GEMM1: qkv = Xb @ Wqkv_t^T + b.  Q scattered to [bh][t][d] PRE-SCALED by
// (1/sqrt(dk))*log2(e); K to [bh][t][d]; V TRANSPOSED to [bh][d][t].
// Grid (12, 64) = 768 blocks = exactly 3 rounds of 256 CUs.
__global__ __launch_bounds__(512, 1) void gemm1_mfma(const u16* __restrict__ A,
                                                     const u16* __restrict__ Bt,
                                                     const float* __restrict__ bias,
                                                     u16* __restrict__ qkv) {
    __shared__ u16 pool[3 * 24576];          // 144 KB
    const int tid = threadIdx.x;
    const int lane = tid & 63, wv = tid >> 6;
    const int lo = lane & 15, quad = lane >> 4;
    // bijective XCD-chunked swizzle: nwg = 768 = 8 * 96
    const int gx = 12;
    int lin = blockIdx.y * gx + blockIdx.x;
    int swz = (lin & 7) * 96 + (lin >> 3);
    const int n0 = (swz % gx) * 256;
    const int m0 = (swz / gx) * 128;
    const int wm = (wv >> 2) * 64, wn = (wv & 3) * 64;   // 2M x 4N waves
    const float scale2 = 0.18033688011112042f;  // (1/8) * log2(e)
    f32x4 acc[4][4] = {};

    gemm_core256<1024>(A, Bt, pool, m0, n0, wm, wn, tid, lo, quad, acc);

    const int whichw = (n0 + wn) >> 10;   // uniform per wave (0=Q,1=K,2=V)
    if (whichw == 2) {
        // V plane: [bh][d][t], pack 4 consecutive t (C-layout rows) per store
#pragma unroll
        for (int i = 0; i < 4; i++) {
            int mb = m0 + wm + i * 16 + quad * 4;
            int b = mb >> 11, t = mb & 2047;
#pragma unroll
            for (int j = 0; j < 4; j++) {
                int n = n0 + wn + j * 16 + lo;
                int rem = n & 1023;
                int h = rem >> 6, d = rem & 63;
                float bn = bias[n];
                ushort4 o;
                o.x = f2bf(acc[i][j][0] + bn);
                o.y = f2bf(acc[i][j][1] + bn);
                o.z = f2bf(acc[i][j][2] + bn);
                o.w = f2bf(acc[i][j][3] + bn);
                *(ushort4*)&qkv[2 * PHT +
                                (((size_t)(b * HEADS + h) * DK + d) * TSEQ + t)] = o;
            }
        }
    } else {
        const float sc = (whichw == 0) ? scale2 : 1.0f;
#pragma unroll
        for (int i = 0; i < 4; i++) {
#pragma unroll
            for (int r = 0; r < 4; r++) {
                int m = m0 + wm + i * 16 + quad * 4 + r;
                int b = m >> 11, t = m & 2047;
#pragma unroll
                for (int j = 0; j < 4; j++) {
                    int n = n0 + wn + j * 16 + lo;
                    float v = (acc[i][j][r] + bias[n]) * sc;
                    int rem = n & 1023;
                    int h = rem >> 6, d = rem & 63;
                    qkv[(size_t)whichw * PHT +
                        (((size_t)(b * HEADS + h) * TSEQ + t) * DK + d)] = f2bf(v);
                }
            }
        }
    }
}

// GEMM2: out = AO @ Wo_t^T + b (fp32 out). Grid (4, 64) = 256 blocks = 1 round.
__global__ __launch_bounds__(512, 1) void gemm2_mfma(const u16* __restrict__ A,
                                                     const u16* __restrict__ Bt,
                                                     const float* __restrict__ bias,
                                                     float* __restrict__ out) {
    __shared__ u16 pool[3 * 24576];
    const int tid = threadIdx.x;
    const int lane = tid & 63, wv = tid >> 6;
    const int lo = lane & 15, quad = lane >> 4;
    // bijective XCD-chunked swizzle: nwg = 256 = 8 * 32
    int lin = blockIdx.y * 4 + blockIdx.x;
    int swz = (lin & 7) * 32 + (lin >> 3);
    const int n0 = (swz & 3) * 256;
    const int m0 = (swz >> 2) * 128;
    const int wm = (wv >> 2) * 64, wn = (wv & 3) * 64;
    f32x4 acc[4][4] = {};

    gemm_core256<1024>(A, Bt, pool, m0, n0, wm, wn, tid, lo, quad, acc);

#pragma unroll
    for (int i = 0; i < 4; i++) {
#pragma unroll
        for (int r = 0; r < 4; r++) {
            int m = m0 + wm + i * 16 + quad * 4 + r;
#pragma unroll
            for (int j = 0; j < 4; j++) {
                int n = n0 + wn + j * 16 + lo;
                out[(size_t)m * EMB + n] = acc[i][j][r] + bias[n];
            }
        }
    }
}

// ---------------------------------------------------------------------------
// MFMA flash attention v4: no-max softmax + double-buffered K/V prefetch.
// Grid (8 pairs, B*H), 256 threads. Block p does q-tiles {p, 15-p} -> 17
// k-iterations of 128 keys. One barrier per iteration; loads for kt+1 fly
// across kt's compute into the other buffer.
// Q (pre-scaled), K: [bh][t][d].  V: [bh][d][t].  Out: [B][T][H][64] bf16.
// LDS 80KB: Ks[2] | Vt[2] | Rr (Q staging overlaid with per-wave P).
// ---------------------------------------------------------------------------
__global__ __launch_bounds__(256, 2) void attn_mfma(const u16* __restrict__ Qg,
                                                    const u16* __restrict__ Kg,
                                                    const u16* __restrict__ Vg,
                                                    u16* __restrict__ AO) {
    __shared__ u16 pool[5 * 8192];
    u16* Rr = pool + 4 * 8192;   // Q staging (128x64) then per-wave P (32x64)

    const int tid = threadIdx.x;
    const int lane = tid & 63, wv = tid >> 6;
    const int lo = lane & 15, quad = lane >> 4;
    const int pair = blockIdx.x, bh = blockIdx.y;
    const size_t base = (size_t)bh * TSEQ * DK;
    const int b = bh >> 4, h = bh & 15;
    const bf16x8 onesf = {0x3F80, 0x3F80, 0x3F80, 0x3F80,
                          0x3F80, 0x3F80, 0x3F80, 0x3F80};

    // stage K(kt2) and V^T(kt2) into buffer bufsel
    auto stageKV = [&](int kt2, int bufsel) {
        u16* Kd = pool + bufsel * 8192;
        u16* Vd = pool + 2 * 8192 + bufsel * 8192;
#pragma unroll
        for (int c = 0; c < 4; c++) {
            int chunk = c * 256 + tid;
            int row = chunk >> 3, p = chunk & 7;
            int pg = p ^ (row & 7);
            gl2lds16(Kg + base + (size_t)(kt2 * 128 + row) * DK + pg * 8,
                     Kd + chunk * 8);
        }
#pragma unroll
        for (int c = 0; c < 4; c++) {
            int chunk = c * 256 + tid;
            int row = chunk >> 4, p = chunk & 15;
            int pg = p ^ (row & 15);
            gl2lds16(Vg + base + (size_t)row * TSEQ + kt2 * 128 + pg * 8,
                     Vd + chunk * 8);
        }
    };

    for (int qi = 0; qi < 2; qi++) {
        const int qt = qi ? (15 - pair) : pair;
        const int q0 = qt * 128;

        __syncthreads();  // prior tile's Ps/Ks/Vt readers done
        // stage Q tile (128x64) into Rr + prologue K0/V0 into buf0
#pragma unroll
        for (int c = 0; c < 4; c++) {
            int chunk = c * 256 + tid;
            int row = chunk >> 3, p = chunk & 7;
            int pg = p ^ (row & 7);
            gl2lds16(Qg + base + (size_t)(q0 + row) * DK + pg * 8, Rr + chunk * 8);
        }
        stageKV(0, 0);
        __syncthreads();  // Q + K0/V0 ready

        // hoist Q B-fragments (kt-invariant; wave-local rows of Rr)
        bf16x8 bq[2][2];
#pragma unroll
        for (int i = 0; i < 2; i++)
#pragma unroll
            for (int hh = 0; hh < 2; hh++) {
                int row = wv * 32 + i * 16 + lo;
                int ch = (hh * 4 + quad) ^ (row & 7);
                bq[i][hh] = *(const bf16x8*)&Rr[row * 64 + ch * 8];
            }

        f32x4 O[2][5] = {};   // [i][0..3 = d-tiles, 4 = row-sum l]

        for (int kt = 0; kt <= qt; kt++) {
            const int cur = kt & 1;
            if (kt) __syncthreads();          // all waves done kt-1; drains prefetch(kt)
            if (kt < qt) stageKV(kt + 1, cur ^ 1);   // flies across kt's compute
            const u16* Ksc = pool + cur * 8192;
            const u16* Vtc = pool + 2 * 8192 + cur * 8192;

            const bool diag = (kt == qt);
            u16* Ps = Rr + wv * 2048;   // per-wave 32 rows x 64 keys (half-tile)

#pragma unroll
            for (int jh = 0; jh < 2; jh++) {
                // S^T = K @ Q^T for 64-key half: st[j2][i]
                f32x4 st[4][2] = {};
#pragma unroll
                for (int hh = 0; hh < 2; hh++) {
#pragma unroll
                    for (int j2 = 0; j2 < 4; j2++) {
                        int row = (jh * 4 + j2) * 16 + lo;
                        int ch = (hh * 4 + quad) ^ (row & 7);
                        bf16x8 ak = *(const bf16x8*)&Ksc[row * 64 + ch * 8];
                        st[j2][0] = __builtin_amdgcn_mfma_f32_16x16x32_bf16(
                            ak, bq[0][hh], st[j2][0], 0, 0, 0);
                        st[j2][1] = __builtin_amdgcn_mfma_f32_16x16x32_bf16(
                            ak, bq[1][hh], st[j2][1], 0, 0, 0);
                    }
                }
                // P = exp2(S^T) (no max), causal-mask diagonal tile only,
                // packed b64 write to Ps[row=qrow][key]
#pragma unroll
                for (int j2 = 0; j2 < 4; j2++) {
#pragma unroll
                    for (int i = 0; i < 2; i++) {
                        float e[4];
#pragma unroll
                        for (int r = 0; r < 4; r++)
                            e[r] = __builtin_amdgcn_exp2f(st[j2][i][r]);
                        if (diag) {
                            int qr = q0 + wv * 32 + i * 16 + lo;
                            int kb = kt * 128 + (jh * 4 + j2) * 16 + quad * 4;
#pragma unroll
                            for (int r = 0; r < 4; r++)
                                if (kb + r > qr) e[r] = 0.f;
                        }
                        uint2 w;
                        w.x = pk2bf(e[0], e[1]);
                        w.y = pk2bf(e[2], e[3]);
                        int rowl = i * 16 + lo;
                        int chp = (2 * j2 + (quad >> 1)) ^ (lo & 7);
                        *(uint2*)&Ps[rowl * 64 + chp * 8 + (quad & 1) * 4] = w;
                    }
                }
                // O += P @ V for this 64-key half (2 MFMA k-steps)
#pragma unroll
                for (int hp = 0; hp < 2; hp++) {
                    bf16x8 ap[2], bv[4];
#pragma unroll
                    for (int i = 0; i < 2; i++) {
                        int rowl = i * 16 + lo;
                        int ch = (4 * hp + quad) ^ (lo & 7);
                        ap[i] = *(const bf16x8*)&Ps[rowl * 64 + ch * 8];
                    }
#pragma unroll
                    for (int jn = 0; jn < 4; jn++) {
                        int vrow = jn * 16 + lo;   // d index
                        int ch = (8 * jh + 4 * hp + quad) ^ (vrow & 15);
                        bv[jn] = *(const bf16x8*)&Vtc[vrow * 128 + ch * 8];
                    }
#pragma unroll
                    for (int i = 0; i < 2; i++) {
#pragma unroll
                        for (int jn = 0; jn < 4; jn++)
                            O[i][jn] = __builtin_amdgcn_mfma_f32_16x16x32_bf16(
                                ap[i], bv[jn], O[i][jn], 0, 0, 0);
                        O[i][4] = __builtin_amdgcn_mfma_f32_16x16x32_bf16(
                            ap[i], onesf, O[i][4], 0, 0, 0);
                    }
                }
            }
        }

        // epilogue: normalize by l, store [B][T][H][DK] bf16
#pragma unroll
        for (int i = 0; i < 2; i++)
#pragma unroll
            for (int r = 0; r < 4; r++) {
                int qrow = q0 + wv * 32 + i * 16 + quad * 4 + r;
                float inv = 1.f / O[i][4][r];
#pragma unroll
                for (int jn = 0; jn < 4; jn++) {
                    int d = jn * 16 + lo;
                    AO[(((size_t)b * TSEQ + qrow) * HEADS + h) * DK + d] =
                        f2bf(O[i][jn][r] * inv);
                }
            }
    }
}

// ---------------------------------------------------------------------------
extern "C" void kernel_launch(void* const* d_in, const int* in_sizes, int n_in,
                              void* d_out, int out_size, void* d_ws, size_t ws_size,
                              hipStream_t stream) {
    const float* x    = (const float*)d_in[0];
    const float* Wqkv = (const float*)d_in[1];
    const float* bqkv = (const float*)d_in[2];
    const float* Wo   = (const float*)d_in[3];
    const float* bo   = (const float*)d_in[4];
    float* out = (float*)d_out;

    // workspace layout (u16 elems): [Xb 8.4M | Wt 3.1M | Wot 1M | QKV 25.2M]
    u16* Xb  = (u16*)d_ws;
    u16* Wt  = Xb + PHT;                    // [3072][1024]
    u16* Wot = Wt + (size_t)NQKV * EMB;     // [1024][1024]
    u16* qkv = Wot + (size_t)EMB * EMB;     // Q,K: [bh][t][d]; V: [bh][d][t]
    u16* AO  = Xb;                          // overlay: Xb dead after gemm1

    convert_x<<<MROWS * EMB / 1024, 256, 0, stream>>>(x, Xb);
    transpose_both<<<dim3(96 + 32, 32), 256, 0, stream>>>(Wqkv, Wo, Wt, Wot);

    gemm1_mfma<<<dim3(NQKV / 256, MROWS / 128), 512, 0, stream>>>(Xb, Wt, bqkv, qkv);
    attn_mfma<<<dim3(8, BATCH * HEADS), 256, 0, stream>>>(
        qkv, qkv + PHT, qkv + 2 * PHT, AO);
    gemm2_mfma<<<dim3(EMB / 256, MROWS / 128), 512, 0, stream>>>(AO, Wot, bo, out);
}

// Round 3
// 226.853 us; speedup vs baseline: 1.1222x; 1.0512x over previous
//
#include <hip/hip_runtime.h>
#include <hip/hip_bf16.h>
#include <math.h>

typedef unsigned short u16;
typedef __attribute__((ext_vector_type(8))) short bf16x8;
typedef __attribute__((ext_vector_type(4))) float f32x4;

#define BATCH 4
#define TSEQ  2048
#define HEADS 16
#define DK    64
#define EMB   1024
#define MROWS 8192            // B*T
#define NQKV  3072
#define PHT   ((size_t)MROWS * EMB)   // 8388608 elems per Q/K/V plane

__device__ __forceinline__ u16 f2bf(float f) {
    union { float f; unsigned int i; } v;
    v.f = f;
    unsigned int x = v.i;
    return (u16)((x + 0x7FFFu + ((x >> 16) & 1u)) >> 16);  // RNE
}

// packed 2xfp32 -> 2xbf16 (RNE) in one u32
__device__ __forceinline__ unsigned int pk2bf(float a, float b) {
    float2 f2; f2.x = a; f2.y = b;
    union { __hip_bfloat162 h; unsigned int u; } cv;
    cv.h = __float22bfloat162_rn(f2);
    return cv.u;
}

// async 16B global->LDS (dest = wave-uniform base + lane*16)
__device__ __forceinline__ void gl2lds16(const u16* g, u16* l) {
    __builtin_amdgcn_global_load_lds(
        (const __attribute__((address_space(1))) unsigned int*)g,
        (__attribute__((address_space(3))) unsigned int*)l, 16, 0, 0);
}

// ---------------------------------------------------------------------------
// prep: fp32 -> bf16 convert (X); both weight transposes in ONE launch
// ---------------------------------------------------------------------------
__global__ __launch_bounds__(256) void convert_x(const float* __restrict__ X,
                                                 u16* __restrict__ Xb) {
    int i = (blockIdx.x * 256 + threadIdx.x) * 4;
    float4 v = *(const float4*)&X[i];
    ushort4 o;
    o.x = f2bf(v.x); o.y = f2bf(v.y); o.z = f2bf(v.z); o.w = f2bf(v.w);
    *(ushort4*)&Xb[i] = o;
}

// bx < 96 -> Wqkv (N=3072); else Wo (N=1024). K=1024 for both.
__global__ __launch_bounds__(256) void transpose_both(const float* __restrict__ Wqkv,
                                                      const float* __restrict__ Wo,
                                                      u16* __restrict__ Wt,
                                                      u16* __restrict__ Wot) {
    __shared__ float tile[32][33];
    const int tx = threadIdx.x & 31, ty = threadIdx.x >> 5;  // 32 x 8
    const int K = 1024;
    const float* W;
    u16* D;
    int N, bx;
    if (blockIdx.x < 96) { W = Wqkv; D = Wt; N = 3072; bx = blockIdx.x; }
    else                 { W = Wo;   D = Wot; N = 1024; bx = blockIdx.x - 96; }
    const int by = blockIdx.y;
#pragma unroll
    for (int s = 0; s < 4; s++)
        tile[ty + 8 * s][tx] = W[(size_t)(by * 32 + ty + 8 * s) * N + bx * 32 + tx];
    __syncthreads();
#pragma unroll
    for (int s = 0; s < 4; s++)
        D[(size_t)(bx * 32 + ty + 8 * s) * K + by * 32 + tx] = f2bf(tile[tx][ty + 8 * s]);
}

// ---------------------------------------------------------------------------
// MFMA GEMM core v3: 128(M) x 256(N) tile, BK=64, 8 waves (2Mx4N), 512 thr.
// Triple-buffered LDS staging (counted vmcnt, never drained in main loop)
// PLUS register-fragment double-buffer: ds_read of tile kt+1 is issued
// BEFORE the MFMA cluster of tile kt, so the LDS pipe (the binding resource:
// 128KB reads + 48KB writes per K-tile ~= 1400-1900 cyc vs 1030 cyc MFMA)
// drains underneath the matrix pipe. ONE barrier per K-tile:
//   lgkmcnt(0)  [frags(kt) in regs for all ds_reads issued last iter]
//   vmcnt(6)    [tile kt+1 landed; kt+2 stays in flight]
//   s_barrier   [collective: buf(kt) free + tile kt+1 visible]
//   stage(kt+3) -> buf(kt)   |  ldfrag(kt+1) -> alternate reg set
//   sched_barrier(0); setprio(1); 32 MFMA(kt); setprio(0)
// Reg sets are NAMED (A/B) via full unroll — runtime-indexed frag arrays
// would spill to scratch (rule #20).
// ---------------------------------------------------------------------------
template <int KDIM>
__device__ __forceinline__ void gemm_core256(const u16* __restrict__ A,
                                             const u16* __restrict__ Bt,
                                             u16* pool,
                                             int m0, int n0, int wm, int wn,
                                             int tid, int lo, int quad,
                                             f32x4 (&acc)[4][4]) {
    constexpr int NT = KDIM / 64;          // 16 K-tiles
    static_assert(NT >= 4 && (NT % 2) == 0, "NT even, >=4");

    // per-thread running global pointers (advance 64 elems per staged tile)
    const u16* ga[2];
    const u16* gb[4];
#pragma unroll
    for (int c = 0; c < 2; c++) {
        int chunk = c * 512 + tid, row = chunk >> 3, p = chunk & 7;
        ga[c] = A + (size_t)(m0 + row) * KDIM + (p ^ (row & 7)) * 8;
    }
#pragma unroll
    for (int c = 0; c < 4; c++) {
        int chunk = c * 512 + tid, row = chunk >> 3, p = chunk & 7;
        gb[c] = Bt + (size_t)(n0 + row) * KDIM + (p ^ (row & 7)) * 8;
    }

    auto stage = [&](int b) {   // 6 gl2lds per wave -> vmcnt +6
        u16* As = pool + b * 24576;
        u16* Bs = As + 8192;
#pragma unroll
        for (int c = 0; c < 2; c++) {
            gl2lds16(ga[c], As + (size_t)(c * 512 + tid) * 8);
            ga[c] += 64;
        }
#pragma unroll
        for (int c = 0; c < 4; c++) {
            gl2lds16(gb[c], Bs + (size_t)(c * 512 + tid) * 8);
            gb[c] += 64;
        }
    };

    bf16x8 afA[2][4], bwA[2][4], afB[2][4], bwB[2][4];

    auto ldfrag = [&](int b, bf16x8 (&af)[2][4], bf16x8 (&bw)[2][4]) {
        const u16* As = pool + b * 24576;
        const u16* Bs = As + 8192;
#pragma unroll
        for (int ks = 0; ks < 2; ks++) {
#pragma unroll
            for (int i = 0; i < 4; i++) {
                int r = wm + i * 16 + lo;
                af[ks][i] = *(const bf16x8*)&As[r * 64 + ((ks * 4 + quad) ^ (r & 7)) * 8];
            }
#pragma unroll
            for (int j = 0; j < 4; j++) {
                int r = wn + j * 16 + lo;
                bw[ks][j] = *(const bf16x8*)&Bs[r * 64 + ((ks * 4 + quad) ^ (r & 7)) * 8];
            }
        }
    };

    auto domfma = [&](bf16x8 (&af)[2][4], bf16x8 (&bw)[2][4]) {
        __builtin_amdgcn_sched_barrier(0);   // keep prefetch ds_reads above MFMA
        __builtin_amdgcn_s_setprio(1);
#pragma unroll
        for (int ks = 0; ks < 2; ks++)
#pragma unroll
            for (int i = 0; i < 4; i++)
#pragma unroll
                for (int j = 0; j < 4; j++)
                    acc[i][j] = __builtin_amdgcn_mfma_f32_16x16x32_bf16(
                        af[ks][i], bw[ks][j], acc[i][j], 0, 0, 0);
        __builtin_amdgcn_s_setprio(0);
    };

    // prologue: fill 3 buffers; read tile-0 fragments into set A
    stage(0); stage(1); stage(2);            // 18 loads in flight
    asm volatile("s_waitcnt vmcnt(12)" ::: "memory");  // my tile-0 loads landed
    __builtin_amdgcn_s_barrier();            // everyone's tile 0 in LDS
    ldfrag(0, afA, bwA);

#pragma unroll
    for (int kt = 0; kt < NT; kt++) {
        if (kt < NT - 1) {
            asm volatile("s_waitcnt lgkmcnt(0)" ::: "memory");   // frags(kt) done
            if (kt < NT - 2)
                asm volatile("s_waitcnt vmcnt(6)" ::: "memory"); // tile kt+1 landed
            else
                asm volatile("s_waitcnt vmcnt(0)" ::: "memory"); // last tile landed
            __builtin_amdgcn_s_barrier();    // collective free + visible
            if (kt + 3 < NT) stage(kt % 3);  // tile kt+3 into freed buffer
            if (kt & 1) ldfrag((kt + 1) % 3, afA, bwA);
            else        ldfrag((kt + 1) % 3, afB, bwB);
        }
        if (kt & 1) domfma(afB, bwB);
        else        domfma(afA, bwA);
    }
}

// GEMM1: qkv = Xb @ Wqkv_t^T + b.  Q scattered to [bh][t][d] PRE-SCALED by
// (1/sqrt(dk))*log2(e); K to [bh][t][d]; V TRANSPOSED to [bh][d][t].
// Grid (12, 64) = 768 blocks = exactly 3 rounds of 256 CUs.
__global__ __launch_bounds__(512, 1) void gemm1_mfma(const u16* __restrict__ A,
                                                     const u16* __restrict__ Bt,
                                                     const float* __restrict__ bias,
                                                     u16* __restrict__ qkv) {
    __shared__ u16 pool[3 * 24576];          // 144 KB
    const int tid = threadIdx.x;
    const int lane = tid & 63, wv = tid >> 6;
    const int lo = lane & 15, quad = lane >> 4;
    // bijective XCD-chunked swizzle: nwg = 768 = 8 * 96
    const int gx = 12;
    int lin = blockIdx.y * gx + blockIdx.x;
    int swz = (lin & 7) * 96 + (lin >> 3);
    const int n0 = (swz % gx) * 256;
    const int m0 = (swz / gx) * 128;
    const int wm = (wv >> 2) * 64, wn = (wv & 3) * 64;   // 2M x 4N waves
    const float scale2 = 0.18033688011112042f;  // (1/8) * log2(e)
    f32x4 acc[4][4] = {};

    gemm_core256<1024>(A, Bt, pool, m0, n0, wm, wn, tid, lo, quad, acc);

    const int whichw = (n0 + wn) >> 10;   // uniform per wave (0=Q,1=K,2=V)
    if (whichw == 2) {
        // V plane: [bh][d][t], pack 4 consecutive t (C-layout rows) per store
#pragma unroll
        for (int i = 0; i < 4; i++) {
            int mb = m0 + wm + i * 16 + quad * 4;
            int b = mb >> 11, t = mb & 2047;
#pragma unroll
            for (int j = 0; j < 4; j++) {
                int n = n0 + wn + j * 16 + lo;
                int rem = n & 1023;
                int h = rem >> 6, d = rem & 63;
                float bn = bias[n];
                ushort4 o;
                o.x = f2bf(acc[i][j][0] + bn);
                o.y = f2bf(acc[i][j][1] + bn);
                o.z = f2bf(acc[i][j][2] + bn);
                o.w = f2bf(acc[i][j][3] + bn);
                *(ushort4*)&qkv[2 * PHT +
                                (((size_t)(b * HEADS + h) * DK + d) * TSEQ + t)] = o;
            }
        }
    } else {
        const float sc = (whichw == 0) ? scale2 : 1.0f;
#pragma unroll
        for (int i = 0; i < 4; i++) {
#pragma unroll
            for (int r = 0; r < 4; r++) {
                int m = m0 + wm + i * 16 + quad * 4 + r;
                int b = m >> 11, t = m & 2047;
#pragma unroll
                for (int j = 0; j < 4; j++) {
                    int n = n0 + wn + j * 16 + lo;
                    float v = (acc[i][j][r] + bias[n]) * sc;
                    int rem = n & 1023;
                    int h = rem >> 6, d = rem & 63;
                    qkv[(size_t)whichw * PHT +
                        (((size_t)(b * HEADS + h) * TSEQ + t) * DK + d)] = f2bf(v);
                }
            }
        }
    }
}

// GEMM2: out = AO @ Wo_t^T + b (fp32 out). Grid (4, 64) = 256 blocks = 1 round.
__global__ __launch_bounds__(512, 1) void gemm2_mfma(const u16* __restrict__ A,
                                                     const u16* __restrict__ Bt,
                                                     const float* __restrict__ bias,
                                                     float* __restrict__ out) {
    __shared__ u16 pool[3 * 24576];
    const int tid = threadIdx.x;
    const int lane = tid & 63, wv = tid >> 6;
    const int lo = lane & 15, quad = lane >> 4;
    // bijective XCD-chunked swizzle: nwg = 256 = 8 * 32
    int lin = blockIdx.y * 4 + blockIdx.x;
    int swz = (lin & 7) * 32 + (lin >> 3);
    const int n0 = (swz & 3) * 256;
    const int m0 = (swz >> 2) * 128;
    const int wm = (wv >> 2) * 64, wn = (wv & 3) * 64;
    f32x4 acc[4][4] = {};

    gemm_core256<1024>(A, Bt, pool, m0, n0, wm, wn, tid, lo, quad, acc);

#pragma unroll
    for (int i = 0; i < 4; i++) {
#pragma unroll
        for (int r = 0; r < 4; r++) {
            int m = m0 + wm + i * 16 + quad * 4 + r;
#pragma unroll
            for (int j = 0; j < 4; j++) {
                int n = n0 + wn + j * 16 + lo;
                out[(size_t)m * EMB + n] = acc[i][j][r] + bias[n];
            }
        }
    }
}

// ---------------------------------------------------------------------------
// MFMA flash attention v4: no-max softmax + double-buffered K/V prefetch.
// Grid (8 pairs, B*H), 256 threads. Block p does q-tiles {p, 15-p} -> 17
// k-iterations of 128 keys. One barrier per iteration; loads for kt+1 fly
// across kt's compute into the other buffer.
// Q (pre-scaled), K: [bh][t][d].  V: [bh][d][t].  Out: [B][T][H][64] bf16.
// LDS 80KB: Ks[2] | Vt[2] | Rr (Q staging overlaid with per-wave P).
// ---------------------------------------------------------------------------
__global__ __launch_bounds__(256, 2) void attn_mfma(const u16* __restrict__ Qg,
                                                    const u16* __restrict__ Kg,
                                                    const u16* __restrict__ Vg,
                                                    u16* __restrict__ AO) {
    __shared__ u16 pool[5 * 8192];
    u16* Rr = pool + 4 * 8192;   // Q staging (128x64) then per-wave P (32x64)

    const int tid = threadIdx.x;
    const int lane = tid & 63, wv = tid >> 6;
    const int lo = lane & 15, quad = lane >> 4;
    const int pair = blockIdx.x, bh = blockIdx.y;
    const size_t base = (size_t)bh * TSEQ * DK;
    const int b = bh >> 4, h = bh & 15;
    const bf16x8 onesf = {0x3F80, 0x3F80, 0x3F80, 0x3F80,
                          0x3F80, 0x3F80, 0x3F80, 0x3F80};

    // stage K(kt2) and V^T(kt2) into buffer bufsel
    auto stageKV = [&](int kt2, int bufsel) {
        u16* Kd = pool + bufsel * 8192;
        u16* Vd = pool + 2 * 8192 + bufsel * 8192;
#pragma unroll
        for (int c = 0; c < 4; c++) {
            int chunk = c * 256 + tid;
            int row = chunk >> 3, p = chunk & 7;
            int pg = p ^ (row & 7);
            gl2lds16(Kg + base + (size_t)(kt2 * 128 + row) * DK + pg * 8,
                     Kd + chunk * 8);
        }
#pragma unroll
        for (int c = 0; c < 4; c++) {
            int chunk = c * 256 + tid;
            int row = chunk >> 4, p = chunk & 15;
            int pg = p ^ (row & 15);
            gl2lds16(Vg + base + (size_t)row * TSEQ + kt2 * 128 + pg * 8,
                     Vd + chunk * 8);
        }
    };

    for (int qi = 0; qi < 2; qi++) {
        const int qt = qi ? (15 - pair) : pair;
        const int q0 = qt * 128;

        __syncthreads();  // prior tile's Ps/Ks/Vt readers done
        // stage Q tile (128x64) into Rr + prologue K0/V0 into buf0
#pragma unroll
        for (int c = 0; c < 4; c++) {
            int chunk = c * 256 + tid;
            int row = chunk >> 3, p = chunk & 7;
            int pg = p ^ (row & 7);
            gl2lds16(Qg + base + (size_t)(q0 + row) * DK + pg * 8, Rr + chunk * 8);
        }
        stageKV(0, 0);
        __syncthreads();  // Q + K0/V0 ready

        // hoist Q B-fragments (kt-invariant; wave-local rows of Rr)
        bf16x8 bq[2][2];
#pragma unroll
        for (int i = 0; i < 2; i++)
#pragma unroll
            for (int hh = 0; hh < 2; hh++) {
                int row = wv * 32 + i * 16 + lo;
                int ch = (hh * 4 + quad) ^ (row & 7);
                bq[i][hh] = *(const bf16x8*)&Rr[row * 64 + ch * 8];
            }

        f32x4 O[2][5] = {};   // [i][0..3 = d-tiles, 4 = row-sum l]

        for (int kt = 0; kt <= qt; kt++) {
            const int cur = kt & 1;
            if (kt) __syncthreads();          // all waves done kt-1; drains prefetch(kt)
            if (kt < qt) stageKV(kt + 1, cur ^ 1);   // flies across kt's compute
            const u16* Ksc = pool + cur * 8192;
            const u16* Vtc = pool + 2 * 8192 + cur * 8192;

            const bool diag = (kt == qt);
            u16* Ps = Rr + wv * 2048;   // per-wave 32 rows x 64 keys (half-tile)

#pragma unroll
            for (int jh = 0; jh < 2; jh++) {
                // S^T = K @ Q^T for 64-key half: st[j2][i]
                f32x4 st[4][2] = {};
#pragma unroll
                for (int hh = 0; hh < 2; hh++) {
#pragma unroll
                    for (int j2 = 0; j2 < 4; j2++) {
                        int row = (jh * 4 + j2) * 16 + lo;
                        int ch = (hh * 4 + quad) ^ (row & 7);
                        bf16x8 ak = *(const bf16x8*)&Ksc[row * 64 + ch * 8];
                        st[j2][0] = __builtin_amdgcn_mfma_f32_16x16x32_bf16(
                            ak, bq[0][hh], st[j2][0], 0, 0, 0);
                        st[j2][1] = __builtin_amdgcn_mfma_f32_16x16x32_bf16(
                            ak, bq[1][hh], st[j2][1], 0, 0, 0);
                    }
                }
                // P = exp2(S^T) (no max), causal-mask diagonal tile only,
                // packed b64 write to Ps[row=qrow][key]
#pragma unroll
                for (int j2 = 0; j2 < 4; j2++) {
#pragma unroll
                    for (int i = 0; i < 2; i++) {
                        float e[4];
#pragma unroll
                        for (int r = 0; r < 4; r++)
                            e[r] = __builtin_amdgcn_exp2f(st[j2][i][r]);
                        if (diag) {
                            int qr = q0 + wv * 32 + i * 16 + lo;
                            int kb = kt * 128 + (jh * 4 + j2) * 16 + quad * 4;
#pragma unroll
                            for (int r = 0; r < 4; r++)
                                if (kb + r > qr) e[r] = 0.f;
                        }
                        uint2 w;
                        w.x = pk2bf(e[0], e[1]);
                        w.y = pk2bf(e[2], e[3]);
                        int rowl = i * 16 + lo;
                        int chp = (2 * j2 + (quad >> 1)) ^ (lo & 7);
                        *(uint2*)&Ps[rowl * 64 + chp * 8 + (quad & 1) * 4] = w;
                    }
                }
                // O += P @ V for this 64-key half (2 MFMA k-steps)
#pragma unroll
                for (int hp = 0; hp < 2; hp++) {
                    bf16x8 ap[2], bv[4];
#pragma unroll
                    for (int i = 0; i < 2; i++) {
                        int rowl = i * 16 + lo;
                        int ch = (4 * hp + quad) ^ (lo & 7);
                        ap[i] = *(const bf16x8*)&Ps[rowl * 64 + ch * 8];
                    }
#pragma unroll
                    for (int jn = 0; jn < 4; jn++) {
                        int vrow = jn * 16 + lo;   // d index
                        int ch = (8 * jh + 4 * hp + quad) ^ (vrow & 15);
                        bv[jn] = *(const bf16x8*)&Vtc[vrow * 128 + ch * 8];
                    }
#pragma unroll
                    for (int i = 0; i < 2; i++) {
#pragma unroll
                        for (int jn = 0; jn < 4; jn++)
                            O[i][jn] = __builtin_amdgcn_mfma_f32_16x16x32_bf16(
                                ap[i], bv[jn], O[i][jn], 0, 0, 0);
                        O[i][4] = __builtin_amdgcn_mfma_f32_16x16x32_bf16(
                            ap[i], onesf, O[i][4], 0, 0, 0);
                    }
                }
            }
        }

        // epilogue: normalize by l, store [B][T][H][DK] bf16
#pragma unroll
        for (int i = 0; i < 2; i++)
#pragma unroll
            for (int r = 0; r < 4; r++) {
                int qrow = q0 + wv * 32 + i * 16 + quad * 4 + r;
                float inv = 1.f / O[i][4][r];
#pragma unroll
                for (int jn = 0; jn < 4; jn++) {
                    int d = jn * 16 + lo;
                    AO[(((size_t)b * TSEQ + qrow) * HEADS + h) * DK + d] =
                        f2bf(O[i][jn][r] * inv);
                }
            }
    }
}

// ---------------------------------------------------------------------------
extern "C" void kernel_launch(void* const* d_in, const int* in_sizes, int n_in,
                              void* d_out, int out_size, void* d_ws, size_t ws_size,
                              hipStream_t stream) {
    const float* x    = (const float*)d_in[0];
    const float* Wqkv = (const float*)d_in[1];
    const float* bqkv = (const float*)d_in[2];
    const float* Wo   = (const float*)d_in[3];
    const float* bo   = (const float*)d_in[4];
    float* out = (float*)d_out;

    // workspace layout (u16 elems): [Xb 8.4M | Wt 3.1M | Wot 1M | QKV 25.2M]
    u16* Xb  = (u16*)d_ws;
    u16* Wt  = Xb + PHT;                    // [3072][1024]
    u16* Wot = Wt + (size_t)NQKV * EMB;     // [1024][1024]
    u16* qkv = Wot + (size_t)EMB * EMB;     // Q,K: [bh][t][d]; V: [bh][d][t]
    u16* AO  = Xb;                          // overlay: Xb dead after gemm1

    convert_x<<<MROWS * EMB / 1024, 256, 0, stream>>>(x, Xb);
    transpose_both<<<dim3(96 + 32, 32), 256, 0, stream>>>(Wqkv, Wo, Wt, Wot);

    gemm1_mfma<<<dim3(NQKV / 256, MROWS / 128), 512, 0, stream>>>(Xb, Wt, bqkv, qkv);
    attn_mfma<<<dim3(8, BATCH * HEADS), 256, 0, stream>>>(
        qkv, qkv + PHT, qkv + 2 * PHT, AO);
    gemm2_mfma<<<dim3(EMB / 256, MROWS / 128), 512, 0, stream>>>(AO, Wot, bo, out);
}